// Round 6
// baseline (87.567 us; speedup 1.0000x reference)
//
#include <hip/hip_runtime.h>
#include <hip/hip_bf16.h>

// Problem geometry
#define HSZ 256
#define WSZ 256
#define BC  16          // b*c
#define NCH 64          // 8x8 window channels
#define PADLO 3         // reflect pad (3,4)

// Tiling: 256 threads = 4 waves; wave w computes rows y0+4w .. y0+4w+3
#define TW 64
#define TH 16
#define RPW 4           // output rows per wave
#define NTHR 256
#define TR (TH + 7)     // 23 halo rows
#define TC 71           // halo cols
#define TSTRIDE 80      // padded LDS row stride (floats)

typedef short bf16x8 __attribute__((ext_vector_type(8)));
typedef float f32x4  __attribute__((ext_vector_type(4)));
typedef unsigned int u32x4 __attribute__((ext_vector_type(4)));

__device__ __forceinline__ int reflect_idx(int i) {
    i = (i < 0) ? -i : i;
    i = (i >= HSZ) ? (2 * (HSZ - 1) - i) : i;
    return i;
}

// fp32 -> bf16 RNE (build kernel only; main kernel uses packed cvt)
__device__ __forceinline__ unsigned short f2bf(float f) {
    unsigned u = __builtin_bit_cast(unsigned, f);
    u += 0x7FFFu + ((u >> 16) & 1u);
    return (unsigned short)(u >> 16);
}

// packed fp32x2 -> bf16x2 (v_cvt_pk_bf16_f32), RNE — same rounding as f2bf.
// NOTE: __hip_bfloat162 is not trivially copyable -> memcpy, not bit_cast.
__device__ __forceinline__ unsigned pk2(float a, float b) {
    __hip_bfloat162 h = __float22bfloat162_rn(make_float2(a, b));
    unsigned r;
    __builtin_memcpy(&r, &h, sizeof(r));
    return r;
}

// ---------------------------------------------------------------------------
// Kernel 1: A = prod_i (I - 2 v_i v_i^T/||v_i||^2), 256 threads.
// 4 lanes per row (lane owns 16 cols); dots reduced via shfl_xor(16,32).
// Wave w emits bf16 A-fragments for m-block mb=w:
//   frag(mb,c): lane l, elem j = A[k = c*32 + (l>>4)*8 + j][mb*16 + (l&15)]
// ws layout: ushort frags[4][2][64][8]  (8 KB)
// ---------------------------------------------------------------------------
__global__ void build_A_frags(const float* __restrict__ v,
                              unsigned short* __restrict__ frags) {
    __shared__ float As[64][64];
    const int t = threadIdx.x;
    const int w = t >> 6;
    const int l = t & 63;
    const int r = (w << 4) | (l & 15);
    const int q = l >> 4;

    float row[16];
#pragma unroll
    for (int c = 0; c < 16; ++c) row[c] = (q * 16 + c == r) ? 1.0f : 0.0f;

    for (int i = 0; i < 64; ++i) {
        const f32x4* vp = (const f32x4*)(v + i * 64 + q * 16);
        f32x4 v0 = vp[0], v1 = vp[1], v2 = vp[2], v3 = vp[3];
        float vv[16];
#pragma unroll
        for (int j = 0; j < 4; ++j) { vv[j] = v0[j]; vv[4+j] = v1[j]; vv[8+j] = v2[j]; vv[12+j] = v3[j]; }

        float s0 = 0, s1 = 0, s2 = 0, s3 = 0, a0 = 0, a1 = 0, a2 = 0, a3 = 0;
#pragma unroll
        for (int c = 0; c < 4; ++c) {
            s0 = fmaf(vv[c],     vv[c],     s0);
            s1 = fmaf(vv[4+c],   vv[4+c],   s1);
            s2 = fmaf(vv[8+c],   vv[8+c],   s2);
            s3 = fmaf(vv[12+c],  vv[12+c],  s3);
            a0 = fmaf(row[c],    vv[c],     a0);
            a1 = fmaf(row[4+c],  vv[4+c],   a1);
            a2 = fmaf(row[8+c],  vv[8+c],   a2);
            a3 = fmaf(row[12+c], vv[12+c],  a3);
        }
        float s  = (s0 + s1) + (s2 + s3);
        float av = (a0 + a1) + (a2 + a3);
        av += __shfl_xor(av, 16); s += __shfl_xor(s, 16);
        av += __shfl_xor(av, 32); s += __shfl_xor(s, 32);

        const float scale = 2.0f * av / s;
#pragma unroll
        for (int c = 0; c < 16; ++c) row[c] = fmaf(-scale, vv[c], row[c]);
    }
#pragma unroll
    for (int c = 0; c < 16; ++c) As[r][q * 16 + c] = row[c];
    __syncthreads();

    const int ln = l & 15, lh = l >> 4;
    const int mb = w;
#pragma unroll
    for (int c2 = 0; c2 < 2; ++c2)
#pragma unroll
        for (int j = 0; j < 8; ++j) {
            float val = As[c2 * 32 + lh * 8 + j][mb * 16 + ln];
            frags[(((mb * 2 + c2) * 64) + l) * 8 + j] = f2bf(val);
        }
}

// ---------------------------------------------------------------------------
// Kernel 2: wave computes 4 output rows x 64 cols x 64 ch via
// mfma_f32_16x16x32_bf16. Dword-centric bf16 path: packed cvt (cvt_pk) into
// dwords d[0..5], fragments = dword windows (even g) / 16-bit merges (odd g).
// Lane's 4 pixel-group results per channel = 4 consecutive px -> nontemporal
// float4 store.
// ---------------------------------------------------------------------------
__global__ __launch_bounds__(256)
void ortho_mfma_kernel(const float* __restrict__ x,
                       const unsigned short* __restrict__ frags,
                       float* __restrict__ out) {
    __shared__ float tile[TR][TSTRIDE];

    const int b  = blockIdx.z;
    const int y0 = blockIdx.y * TH;
    const int x0 = blockIdx.x * TW;
    const float* __restrict__ xb = x + (size_t)b * (HSZ * WSZ);

    const int tx = threadIdx.x;   // lane 0..63
    const int ty = threadIdx.y;   // wave 0..3
    const int tid = ty * TW + tx;

    // --- Stage halo tile. 16 lane-groups <-> rows; fixed per-lane columns,
    // reflect-col computed once and reused for this thread's rows.
    {
        const int grp = tid >> 4;       // 0..15
        const int lk  = tid & 15;       // 0..15
        int gcols[5];
#pragma unroll
        for (int k = 0; k < 5; ++k) {
            const int c = lk + 16 * k;
            gcols[k] = (c < TC) ? reflect_idx(x0 + c - PADLO) : 0;
        }
        for (int r = grp; r < TR; r += 16) {
            const float* rowp = xb + (size_t)reflect_idx(y0 + r - PADLO) * WSZ;
#pragma unroll
            for (int k = 0; k < 5; ++k) {
                const int c = lk + 16 * k;
                if (c < TC) tile[r][c] = rowp[gcols[k]];
            }
        }
    }

    const int ln = tx & 15, lh = tx >> 4;

    // Hoist A fragments (8 x 16B, L2-hot, reused for all 4 rows)
    bf16x8 af[4][2];
#pragma unroll
    for (int mb = 0; mb < 4; ++mb)
#pragma unroll
        for (int c = 0; c < 2; ++c)
            af[mb][c] = *(const bf16x8*)(frags + ((mb * 2 + c) * 64 + tx) * 8);

    __syncthreads();

#pragma unroll
    for (int ry = 0; ry < RPW; ++ry) {
        const int tyr = ty * RPW + ry;      // tile-relative output row
        const int y   = y0 + tyr;

        // Per k-chunk: 12 fp32 (elems 0..11; only 0..10 used) -> 6 packed dwords
        unsigned d[2][6];
#pragma unroll
        for (int c = 0; c < 2; ++c) {
            const f32x4* rp = (const f32x4*)&tile[tyr + 4 * c + lh][4 * ln];
            f32x4 q0 = rp[0], q1 = rp[1], q2 = rp[2];
            d[c][0] = pk2(q0[0], q0[1]);
            d[c][1] = pk2(q0[2], q0[3]);
            d[c][2] = pk2(q1[0], q1[1]);
            d[c][3] = pk2(q1[2], q1[3]);
            d[c][4] = pk2(q2[0], q2[1]);
            d[c][5] = pk2(q2[2], q2[3]);
        }

        // Fragments: g even -> dword window; g odd -> 16-bit merges (alignbit)
        bf16x8 bfr[2][4];
#pragma unroll
        for (int c = 0; c < 2; ++c) {
            const unsigned* dc = d[c];
            u32x4 w0 = { dc[0], dc[1], dc[2], dc[3] };                      // g=0: e0..7
            u32x4 w2 = { dc[1], dc[2], dc[3], dc[4] };                      // g=2: e2..9
            u32x4 w1 = { (dc[0] >> 16) | (dc[1] << 16),                    // g=1: e1..8
                         (dc[1] >> 16) | (dc[2] << 16),
                         (dc[2] >> 16) | (dc[3] << 16),
                         (dc[3] >> 16) | (dc[4] << 16) };
            u32x4 w3 = { (dc[1] >> 16) | (dc[2] << 16),                    // g=3: e3..10
                         (dc[2] >> 16) | (dc[3] << 16),
                         (dc[3] >> 16) | (dc[4] << 16),
                         (dc[4] >> 16) | (dc[5] << 16) };
            bfr[c][0] = __builtin_bit_cast(bf16x8, w0);
            bfr[c][1] = __builtin_bit_cast(bf16x8, w1);
            bfr[c][2] = __builtin_bit_cast(bf16x8, w2);
            bfr[c][3] = __builtin_bit_cast(bf16x8, w3);
        }

        float* __restrict__ outb =
            out + (size_t)b * NCH * (HSZ * WSZ) + (size_t)y * WSZ + x0 + 4 * ln;

#pragma unroll
        for (int mb = 0; mb < 4; ++mb) {
            f32x4 acc[4];
#pragma unroll
            for (int g = 0; g < 4; ++g) {
                acc[g] = (f32x4){0.0f, 0.0f, 0.0f, 0.0f};
                acc[g] = __builtin_amdgcn_mfma_f32_16x16x32_bf16(af[mb][0], bfr[0][g], acc[g], 0, 0, 0);
                acc[g] = __builtin_amdgcn_mfma_f32_16x16x32_bf16(af[mb][1], bfr[1][g], acc[g], 0, 0, 0);
            }
#pragma unroll
            for (int r = 0; r < 4; ++r) {
                const int ch = mb * 16 + lh * 4 + r;
                f32x4 vv = { acc[0][r], acc[1][r], acc[2][r], acc[3][r] };
                __builtin_nontemporal_store(vv, (f32x4*)&outb[(size_t)ch * (HSZ * WSZ)]);
            }
        }
    }
}

// ---------------------------------------------------------------------------
extern "C" void kernel_launch(void* const* d_in, const int* in_sizes, int n_in,
                              void* d_out, int out_size, void* d_ws, size_t ws_size,
                              hipStream_t stream) {
    const float* x = (const float*)d_in[0];        // [2,8,256,256] fp32
    const float* v = (const float*)d_in[1];        // [64,64] fp32
    float* outp = (float*)d_out;                   // [16,64,256,256] fp32
    unsigned short* frags = (unsigned short*)d_ws; // 4*2*64*8 bf16 = 8 KB

    build_A_frags<<<1, 256, 0, stream>>>(v, frags);

    dim3 grid(WSZ / TW, HSZ / TH, BC);             // 4 x 16 x 16 = 1024 blocks
    dim3 block(TW, TH / RPW);                      // 256 threads = 4 waves
    ortho_mfma_kernel<<<grid, block, 0, stream>>>(x, frags, outp);
}